// Round 22
// baseline (184.181 us; speedup 1.0000x reference)
//
#include <hip/hip_runtime.h>

#define S_LEN 4096
#define NROWS 16384          // B*S

typedef float f32x4 __attribute__((ext_vector_type(4)));
typedef _Float16 f16x8 __attribute__((ext_vector_type(8)));
typedef _Float16 f16x4 __attribute__((ext_vector_type(4)));

__device__ __forceinline__ unsigned short f2h(float f) {
  _Float16 h = (_Float16)f;
  return __builtin_bit_cast(unsigned short, h);
}

__device__ __forceinline__ float ex2(float x) {   // native v_exp_f32 (2^x)
  return __builtin_amdgcn_exp2f(x);
}

__device__ __forceinline__ void gload16(const void* g, void* l) {
  __builtin_amdgcn_global_load_lds(
      (const __attribute__((address_space(1))) void*)g,
      (__attribute__((address_space(3))) void*)l, 16, 0, 0);
}

// ---------------- weight convert (fp32 -> fp16) ----------------
__global__ void cw_kernel(const float* __restrict__ Wq, const float* __restrict__ Wk,
                          unsigned short* __restrict__ Wqb, unsigned short* __restrict__ Wkb) {
  const int i = (blockIdx.x * 256 + threadIdx.x) * 8;
  if (i >= 131072) return;
  unsigned short tmp[8] __attribute__((aligned(16)));
#pragma unroll
  for (int u = 0; u < 8; ++u) tmp[u] = f2h(Wq[i + u]);
  *(uint4*)(Wqb + i) = ((const uint4*)tmp)[0];
#pragma unroll
  for (int u = 0; u < 8; ++u) tmp[u] = f2h(Wk[i + u]);
  *(uint4*)(Wkb + i) = ((const uint4*)tmp)[0];
}

// ---------------- fused prep: proj (blocks 0..511) + V transpose (blocks 512..1535) ----
// proj: out = fp16((X[16384x512] * W^T[512x256] + b) * sc); sc_Q = scale * log2(e).
// vt:   V [B][S][D] f32 -> Vt [B][D][S] fp16. (r20: fusion saved ~3 us -- kept.)
__global__ __launch_bounds__(256, 4) void prep_kernel(
    const float* __restrict__ Xq, const float* __restrict__ Xk,
    const unsigned short* __restrict__ Wqb, const unsigned short* __restrict__ Wkb,
    const float* __restrict__ bq, const float* __restrict__ bk,
    unsigned short* __restrict__ Qb, unsigned short* __restrict__ Kb,
    const float* __restrict__ scale_ptr,
    const float* __restrict__ V, unsigned short* __restrict__ Vt) {
  __shared__ char shm[40960];   // proj: sx 8K + sw 32K; vt: tile 16.6K (union)
  const int tid = threadIdx.x;

  if (blockIdx.x >= 512) {      // ---------------- vt half ----------------
    const int vid = blockIdx.x - 512;
    const int b = vid >> 8, d0 = ((vid >> 6) & 3) * 64, s0 = (vid & 63) * 64;
    float (*tile)[65] = (float(*)[65])shm;
    {
      const int r = tid >> 2, cs = (tid & 3) * 16;
      const float* src = V + ((long)b * S_LEN + s0 + r) * 256 + d0 + cs;
#pragma unroll
      for (int u = 0; u < 4; ++u) {
        const f32x4 v = __builtin_nontemporal_load((const f32x4*)(src + 4 * u));
        tile[r][cs + 4 * u + 0] = v[0]; tile[r][cs + 4 * u + 1] = v[1];
        tile[r][cs + 4 * u + 2] = v[2]; tile[r][cs + 4 * u + 3] = v[3];
      }
    }
    __syncthreads();
    {
      const int d = tid >> 2, ss = (tid & 3) * 16;
      unsigned short tmp[16] __attribute__((aligned(16)));
#pragma unroll
      for (int u = 0; u < 16; ++u) tmp[u] = f2h(tile[ss + u][d]);
      unsigned short* dst = Vt + ((long)b * 256 + d0 + d) * S_LEN + s0 + ss;
      *(uint4*)dst = ((const uint4*)tmp)[0];
      *((uint4*)dst + 1) = ((const uint4*)tmp)[1];
    }
    return;
  }

  // ---------------- proj half ----------------
  const int z = blockIdx.x & 1;
  const int rowbase = (blockIdx.x >> 1) * 64;
  const int lane = tid & 63, w = tid >> 6;
  const int h = lane >> 4, cc = lane & 15;
  const float* X = z ? Xk : Xq;
  const unsigned short* Wb = z ? Wkb : Wqb;
  const float* bias = z ? bk : bq;
  unsigned short* out = z ? Kb : Qb;
  const float sc = z ? 1.f : scale_ptr[0] * 1.44269504088896340736f;

  char* const sx = shm;          // X tile [64][64] fp16, swizzled
  char* const sw = shm + 8192;   // W tile [256][64] fp16, swizzled

  f32x4 acc[16];
  const f32x4 fz = {0.f, 0.f, 0.f, 0.f};
#pragma unroll
  for (int nf = 0; nf < 16; ++nf) acc[nf] = fz;

  for (int kstep = 0; kstep < 8; ++kstep) {
    const int k0 = kstep * 64;
    __syncthreads();  // previous compute reads done before overwrite
    {  // X stage: fp32 nt-load -> fp16 -> swizzled ds_write_b128
      const int r = tid >> 2;
      const int cb0 = (tid & 3) * 2;
      const float* src = X + (long)(rowbase + r) * 512 + k0 + (tid & 3) * 16;
      float xv[16];
#pragma unroll
      for (int u = 0; u < 4; ++u) {
        const f32x4 v = __builtin_nontemporal_load((const f32x4*)(src + 4 * u));
        xv[4 * u + 0] = v[0]; xv[4 * u + 1] = v[1];
        xv[4 * u + 2] = v[2]; xv[4 * u + 3] = v[3];
      }
      unsigned short tmp[16] __attribute__((aligned(16)));
#pragma unroll
      for (int u = 0; u < 16; ++u) tmp[u] = f2h(xv[u]);
      *(uint4*)(sx + r * 128 + ((cb0 ^ (r & 7)) * 16)) = ((const uint4*)tmp)[0];
      *(uint4*)(sx + r * 128 + (((cb0 + 1) ^ (r & 7)) * 16)) = ((const uint4*)tmp)[1];
    }
    // W stage: global_load_lds, linear LDS dest + inverse-swizzled global source
#pragma unroll
    for (int i = 0; i < 8; ++i) {
      const int off = w * 8192 + i * 1024 + lane * 16;
      const int row = off >> 7;
      const int lcb = (lane & 7) ^ (row & 7);
      gload16(Wb + (long)row * 512 + k0 + lcb * 8, sw + w * 8192 + i * 1024);
    }
    __syncthreads();
#pragma unroll
    for (int ks = 0; ks < 2; ++ks) {
      const int rl = 16 * w + cc;
      const f16x8 af = *(const f16x8*)(sx + rl * 128 + (((h + 4 * ks) ^ (rl & 7)) * 16));
#pragma unroll
      for (int nf = 0; nf < 16; ++nf) {
        const int n = cc + 16 * nf;
        const f16x8 bf = *(const f16x8*)(sw + n * 128 + (((h + 4 * ks) ^ (n & 7)) * 16));
        acc[nf] = __builtin_amdgcn_mfma_f32_16x16x32_f16(af, bf, acc[nf], 0, 0, 0);
      }
    }
  }
#pragma unroll
  for (int nf = 0; nf < 16; ++nf) {
    const float bv = bias[cc + 16 * nf];
#pragma unroll
    for (int r = 0; r < 4; ++r) {
      const long grow = rowbase + 16 * w + 4 * h + r;
      out[grow * 256 + cc + 16 * nf] = f2h((acc[nf][r] + bv) * sc);
    }
  }
}

// ---------------- flash attention (r19 loop + late-issue staging) ----------------
// 256-thread block (BQ=64), KVBLK=32 dbuf, 16 q-rows/wave, 2 blocks/CU, single
// __syncthreads per iter. log2-domain scores + native exp2; defer-max THR=12;
// fp16 normalized partials. NEW: stage(t+1) issued AFTER QK^T (was top-of-loop) --
// the 8 gload_lds LDS-writes no longer head-of-line-block QK^T's ds_reads; their
// latency hides under softmax+PV, and the end-of-iter __syncthreads vmcnt drain
// still guarantees buf^1 completeness before iter t+1 (sync structure unchanged).
__global__ __launch_bounds__(256, 2) void attn_kernel(
    const unsigned short* __restrict__ Qb, const unsigned short* __restrict__ Kb,
    const unsigned short* __restrict__ Vt, float* __restrict__ out0,
    unsigned short* __restrict__ p16, float2* __restrict__ stats,
    int* __restrict__ cnt, int nsplit, int nchunks) {
  extern __shared__ char smem[];
  const int tid = threadIdx.x;
  const int lane = tid & 63, w = tid >> 6;
  const int h = lane >> 4, c = lane & 15;

  // ---- claim a work item from this XCD's chunk (exactly-once: tickets <32) ----
  int* s_item_p = (int*)(smem + 69632);
  if (tid == 0) {
    const unsigned x = __builtin_amdgcn_s_getreg(6164) & 7u;  // HW_REG_XCC_ID(20),off0,sz4
    const int pref = (int)x * nchunks / 8;
    int item = 0;
    for (int k = 0; k < nchunks; ++k) {
      const int ch = (pref + k) % nchunks;
      const int t = atomicAdd(cnt + ch, 1);
      if (t < 32) { item = ch * 32 + t; break; }
    }
    *s_item_p = item;
  }
  __syncthreads();
  const int nid = *s_item_p;
  const int gqt = nid & 255;      // q-tile among 256 (BQ=64)
  const int split = nid >> 8;

  const int b = gqt >> 6;
  const int qrow0 = (gqt & 63) * 64;
  const long brow = (long)b * S_LEN;

  const int kv_len = S_LEN / nsplit;
  const int kv0 = split * kv_len;
  const int nit = kv_len / 32;

  // Q fragments: 16 q-rows, 8 k-steps (scale*log2e pre-folded into Q)
  f16x8 qf[8];
  {
    const unsigned short* qbase = Qb + (brow + qrow0 + w * 16 + c) * 256 + h * 8;
#pragma unroll
    for (int kk = 0; kk < 8; ++kk)
      qf[kk] = *(const f16x8*)(qbase + kk * 32);
  }

  f32x4 O[16];
  float mrun[4], lrun[4];   // log2-domain; lrun = per-lane partial (epilogue reduce)
  const f32x4 fz = {0.f, 0.f, 0.f, 0.f};
#pragma unroll
  for (int nfd = 0; nfd < 16; ++nfd) O[nfd] = fz;
#pragma unroll
  for (int r = 0; r < 4; ++r) { mrun[r] = -1e30f; lrun[r] = 0.f; }

  const unsigned short* kbB = Kb + brow * 256;
  const unsigned short* vbB = Vt + (long)b * 256 * S_LEN;

  auto stage = [&](int buf, int it) {
    const int kvb = kv0 + it * 32;
#pragma unroll
    for (int i = 0; i < 4; ++i) {
      const int off = i * 4096 + tid * 16;
      {  // K tile [32][256] fp16, rows 512B; inverse-swizzled source
        const int row = off >> 9;
        const int lcb = ((off >> 4) & 31) ^ (row & 7);
        gload16(kbB + (long)(kvb + row) * 256 + lcb * 8, smem + buf * 16384 + off);
      }
      {  // V tile [256][32] fp16, rows 64B; inverse-swizzled source (dr>>1 swizzle)
        const int drow = off >> 6;
        const int lcb = ((off >> 4) & 3) ^ ((drow >> 1) & 3);
        gload16(vbB + (long)drow * S_LEN + kvb + lcb * 8,
                smem + 32768 + buf * 16384 + off);
      }
    }
  };

  char* const pt = smem + 65536 + w * 1024;  // per-wave P [16][32] fp16, rows 64B

  stage(0, 0);
  __syncthreads();

  for (int t = 0; t < nit; ++t) {
    const int buf = t & 1;
    const char* kt = smem + buf * 16384;
    const char* vl = smem + 32768 + buf * 16384;

    // ---- QK^T (reads issue first -- no staging burst ahead of them) ----
    f32x4 s[2];
    s[0] = fz; s[1] = fz;
    __builtin_amdgcn_s_setprio(1);
#pragma unroll
    for (int kk = 0; kk < 8; ++kk) {
#pragma unroll
      for (int nf = 0; nf < 2; ++nf) {
        const int r = c + 16 * nf;                  // kv row 0..31
        const int cb = ((4 * kk + h) ^ (r & 7)) & 31;
        const f16x8 kf = *(const f16x8*)(kt + r * 512 + cb * 16);
        s[nf] = __builtin_amdgcn_mfma_f32_16x16x32_f16(qf[kk], kf, s[nf], 0, 0, 0);
      }
    }
    __builtin_amdgcn_s_setprio(0);

    // ---- stage(t+1): issued after QK^T; latency hides under softmax+PV ----
    if (t + 1 < nit) stage(buf ^ 1, t + 1);

    // ---- online softmax with defer-max (THR=12, log2 domain, native exp2) ----
    {
      bool ok = true;
#pragma unroll
      for (int r = 0; r < 4; ++r)
        ok &= (fmaxf(s[0][r], s[1][r]) <= mrun[r] + 12.f);
      if (__all(ok)) {  // fast path: no shfl, no rescale
#pragma unroll
        for (int r = 0; r < 4; ++r) {
          const float p0 = ex2(s[0][r] - mrun[r]);
          const float p1 = ex2(s[1][r] - mrun[r]);
          s[0][r] = p0; s[1][r] = p1;
          lrun[r] += p0 + p1;
        }
      } else {          // slow path: full max-reduce + rescale (rare)
#pragma unroll
        for (int r = 0; r < 4; ++r) {
          float mx = fmaxf(s[0][r], s[1][r]);
          mx = fmaxf(mx, __shfl_xor(mx, 1));
          mx = fmaxf(mx, __shfl_xor(mx, 2));
          mx = fmaxf(mx, __shfl_xor(mx, 4));
          mx = fmaxf(mx, __shfl_xor(mx, 8));
          const float mnew = fmaxf(mrun[r], mx);
          const float alpha = ex2(mrun[r] - mnew);
          const float p0 = ex2(s[0][r] - mnew);
          const float p1 = ex2(s[1][r] - mnew);
          s[0][r] = p0; s[1][r] = p1;
          lrun[r] = lrun[r] * alpha + p0 + p1;
          mrun[r] = mnew;
#pragma unroll
          for (int nfd = 0; nfd < 16; ++nfd) O[nfd][r] *= alpha;
        }
      }
      // P -> LDS, rows R=4h+r (64B), col C=c+16nf; blk = (C>>3) ^ r ^ h
#pragma unroll
      for (int nf = 0; nf < 2; ++nf)
#pragma unroll
        for (int r = 0; r < 4; ++r) {
          const int C = c + 16 * nf;
          const int blk = ((C >> 3) ^ r ^ h) & 3;
          *(unsigned short*)(pt + (4 * h + r) * 64 + blk * 16 + (C & 7) * 2) =
              f2h(s[nf][r]);
        }
    }
    asm volatile("" ::: "memory");  // order P writes before P reads (type-punned LDS)

    // ---- P·V ----
    __builtin_amdgcn_s_setprio(1);
    {
      const f16x8 pa = *(const f16x8*)(pt + c * 64 + (((h ^ c ^ (c >> 2)) & 3) * 16));
#pragma unroll
      for (int nfd = 0; nfd < 16; ++nfd) {
        const int dr = c + 16 * nfd;
        const f16x8 vf = *(const f16x8*)(vl + dr * 64 + (((h ^ (dr >> 1)) & 3) * 16));
        O[nfd] = __builtin_amdgcn_mfma_f32_16x16x32_f16(pa, vf, O[nfd], 0, 0, 0);
      }
    }
    __builtin_amdgcn_s_setprio(0);
    __syncthreads();   // full drain: staged loads landed, all reads of buf done
  }

  // ---- epilogue: reduce per-lane l partials across the 16-lane row group ----
#pragma unroll
  for (int r = 0; r < 4; ++r) {
    float l = lrun[r];
    l += __shfl_xor(l, 1); l += __shfl_xor(l, 2);
    l += __shfl_xor(l, 4); l += __shfl_xor(l, 8);
    lrun[r] = l;
  }

  const long rowg0 = brow + qrow0 + w * 16 + 4 * h;
  float inv[4];
#pragma unroll
  for (int r = 0; r < 4; ++r) inv[r] = 1.f / lrun[r];

  if (nsplit == 1) {
#pragma unroll
    for (int nfd = 0; nfd < 16; ++nfd)
#pragma unroll
      for (int r = 0; r < 4; ++r)
        out0[(rowg0 + r) * 256 + c + 16 * nfd] = O[nfd][r] * inv[r];
  } else {
    // normalized fp16 partial: On = O / l  (bounded by max|v|, fp16-safe)
    unsigned short* dst = p16 + (long)split * NROWS * 256;
#pragma unroll
    for (int nfd = 0; nfd < 16; ++nfd)
#pragma unroll
      for (int r = 0; r < 4; ++r)
        dst[(rowg0 + r) * 256 + c + 16 * nfd] = f2h(O[nfd][r] * inv[r]);
    if (c == 0) {
#pragma unroll
      for (int r = 0; r < 4; ++r)
        stats[(long)split * NROWS + rowg0 + r] = make_float2(mrun[r], lrun[r]);
    }
  }
}

// ---------------- merge KV-split partials (fp16 normalized, log2-domain stats) ----------------
__global__ __launch_bounds__(256) void merge_kernel(float* __restrict__ out0,
                                                    const unsigned short* __restrict__ p16,
                                                    const float2* __restrict__ stats,
                                                    int nsplit) {
  const int i4 = blockIdx.x * 256 + threadIdx.x;  // float4 index, total 1048576
  const int row = i4 >> 6;
  float2 st[4];
#pragma unroll
  for (int s = 0; s < 4; ++s)
    st[s] = (s < nsplit) ? stats[s * NROWS + row] : make_float2(-1e30f, 0.f);
  const float m = fmaxf(fmaxf(st[0].x, st[1].x), fmaxf(st[2].x, st[3].x));
  float wgt[4], den = 0.f;
#pragma unroll
  for (int s = 0; s < 4; ++s) {
    wgt[s] = st[s].y * __builtin_amdgcn_exp2f(st[s].x - m);  // l_s * 2^(m_s - m)
    den += wgt[s];
  }
  const float invd = 1.f / den;
  float ax = 0.f, ay = 0.f, az = 0.f, aw = 0.f;
#pragma unroll
  for (int s = 0; s < 4; ++s) {
    if (s < nsplit) {
      const f16x4 v = ((const f16x4*)(p16 + (long)s * NROWS * 256))[i4];
      ax += (float)v[0] * wgt[s]; ay += (float)v[1] * wgt[s];
      az += (float)v[2] * wgt[s]; aw += (float)v[3] * wgt[s];
    }
  }
  const f32x4 res = {ax * invd, ay * invd, az * invd, aw * invd};
  ((f32x4*)out0)[i4] = res;
}

extern "C" void kernel_launch(void* const* d_in, const int* in_sizes, int n_in,
                              void* d_out, int out_size, void* d_ws, size_t ws_size,
                              hipStream_t stream) {
  const float* query = (const float*)d_in[0];
  const float* key   = (const float*)d_in[1];
  const float* value = (const float*)d_in[2];
  const float* Wq    = (const float*)d_in[3];
  const float* bq    = (const float*)d_in[4];
  const float* Wk    = (const float*)d_in[5];
  const float* bk    = (const float*)d_in[6];
  const float* scale = (const float*)d_in[7];
  float* out = (float*)d_out;

  char* ws = (char*)d_ws;
  unsigned short* Wqb = (unsigned short*)(ws);            // 256 KB
  unsigned short* Wkb = (unsigned short*)(ws + 262144);   // 256 KB
  unsigned short* Qb  = (unsigned short*)(ws + 524288);   // 8 MB
  unsigned short* Kb  = (unsigned short*)(ws + 8912896);  // 8 MB
  unsigned short* Vt  = (unsigned short*)(ws + 17301504); // 8 MB
  int* cnt            = (int*)(ws + 25690112);            // 4 KB
  float2* stats       = (float2*)(ws + 25694208);         // 512 KB
  unsigned short* p16 = (unsigned short*)(ws + 26218496); // 2 x 8 MB fp16 partials

  int nsplit = 1;
  if (ws_size >= 42995712) nsplit = 2;   // BQ=64: 512 blocks = exactly 2/CU
  const int nblk = 256 * nsplit;
  const int nchunks = nblk / 32;

  hipMemsetAsync(cnt, 0, 64, stream);
  cw_kernel<<<64, 256, 0, stream>>>(Wq, Wk, Wqb, Wkb);
  prep_kernel<<<1536, 256, 0, stream>>>(query, key, Wqb, Wkb, bq, bk, Qb, Kb,
                                        scale, value, Vt);
  hipFuncSetAttribute((const void*)attn_kernel,
                      hipFuncAttributeMaxDynamicSharedMemorySize, 69648);
  attn_kernel<<<nblk, 256, 69648, stream>>>(Qb, Kb, Vt, out, p16,
                                            stats, cnt, nsplit, nchunks);
  if (nsplit > 1)
    merge_kernel<<<4096, 256, 0, stream>>>(out, p16, stats, nsplit);
}

// Round 23
// 178.341 us; speedup vs baseline: 1.0327x; 1.0327x over previous
//
#include <hip/hip_runtime.h>

#define S_LEN 4096
#define NROWS 16384          // B*S

typedef float f32x4 __attribute__((ext_vector_type(4)));
typedef _Float16 f16x8 __attribute__((ext_vector_type(8)));
typedef _Float16 f16x4 __attribute__((ext_vector_type(4)));

__device__ __forceinline__ unsigned short f2h(float f) {
  _Float16 h = (_Float16)f;
  return __builtin_bit_cast(unsigned short, h);
}

__device__ __forceinline__ float ex2(float x) {   // native v_exp_f32 (2^x)
  return __builtin_amdgcn_exp2f(x);
}

__device__ __forceinline__ void gload16(const void* g, void* l) {
  __builtin_amdgcn_global_load_lds(
      (const __attribute__((address_space(1))) void*)g,
      (__attribute__((address_space(3))) void*)l, 16, 0, 0);
}

// ---------------- weight convert (fp32 -> fp16) ----------------
__global__ void cw_kernel(const float* __restrict__ Wq, const float* __restrict__ Wk,
                          unsigned short* __restrict__ Wqb, unsigned short* __restrict__ Wkb) {
  const int i = (blockIdx.x * 256 + threadIdx.x) * 8;
  if (i >= 131072) return;
  unsigned short tmp[8] __attribute__((aligned(16)));
#pragma unroll
  for (int u = 0; u < 8; ++u) tmp[u] = f2h(Wq[i + u]);
  *(uint4*)(Wqb + i) = ((const uint4*)tmp)[0];
#pragma unroll
  for (int u = 0; u < 8; ++u) tmp[u] = f2h(Wk[i + u]);
  *(uint4*)(Wkb + i) = ((const uint4*)tmp)[0];
}

// ---------------- fused prep: proj (blocks 0..511) + V transpose (blocks 512..1535) ----
// proj: out = fp16((X[16384x512] * W^T[512x256] + b) * sc); sc_Q = scale * log2(e).
// vt:   V [B][S][D] f32 -> Vt [B][D][S] fp16. (r20: fusion saved ~3 us -- kept.)
__global__ __launch_bounds__(256, 4) void prep_kernel(
    const float* __restrict__ Xq, const float* __restrict__ Xk,
    const unsigned short* __restrict__ Wqb, const unsigned short* __restrict__ Wkb,
    const float* __restrict__ bq, const float* __restrict__ bk,
    unsigned short* __restrict__ Qb, unsigned short* __restrict__ Kb,
    const float* __restrict__ scale_ptr,
    const float* __restrict__ V, unsigned short* __restrict__ Vt) {
  __shared__ char shm[40960];   // proj: sx 8K + sw 32K; vt: tile 16.6K (union)
  const int tid = threadIdx.x;

  if (blockIdx.x >= 512) {      // ---------------- vt half ----------------
    const int vid = blockIdx.x - 512;
    const int b = vid >> 8, d0 = ((vid >> 6) & 3) * 64, s0 = (vid & 63) * 64;
    float (*tile)[65] = (float(*)[65])shm;
    {
      const int r = tid >> 2, cs = (tid & 3) * 16;
      const float* src = V + ((long)b * S_LEN + s0 + r) * 256 + d0 + cs;
#pragma unroll
      for (int u = 0; u < 4; ++u) {
        const f32x4 v = __builtin_nontemporal_load((const f32x4*)(src + 4 * u));
        tile[r][cs + 4 * u + 0] = v[0]; tile[r][cs + 4 * u + 1] = v[1];
        tile[r][cs + 4 * u + 2] = v[2]; tile[r][cs + 4 * u + 3] = v[3];
      }
    }
    __syncthreads();
    {
      const int d = tid >> 2, ss = (tid & 3) * 16;
      unsigned short tmp[16] __attribute__((aligned(16)));
#pragma unroll
      for (int u = 0; u < 16; ++u) tmp[u] = f2h(tile[ss + u][d]);
      unsigned short* dst = Vt + ((long)b * 256 + d0 + d) * S_LEN + s0 + ss;
      *(uint4*)dst = ((const uint4*)tmp)[0];
      *((uint4*)dst + 1) = ((const uint4*)tmp)[1];
    }
    return;
  }

  // ---------------- proj half ----------------
  const int z = blockIdx.x & 1;
  const int rowbase = (blockIdx.x >> 1) * 64;
  const int lane = tid & 63, w = tid >> 6;
  const int h = lane >> 4, cc = lane & 15;
  const float* X = z ? Xk : Xq;
  const unsigned short* Wb = z ? Wkb : Wqb;
  const float* bias = z ? bk : bq;
  unsigned short* out = z ? Kb : Qb;
  const float sc = z ? 1.f : scale_ptr[0] * 1.44269504088896340736f;

  char* const sx = shm;          // X tile [64][64] fp16, swizzled
  char* const sw = shm + 8192;   // W tile [256][64] fp16, swizzled

  f32x4 acc[16];
  const f32x4 fz = {0.f, 0.f, 0.f, 0.f};
#pragma unroll
  for (int nf = 0; nf < 16; ++nf) acc[nf] = fz;

  for (int kstep = 0; kstep < 8; ++kstep) {
    const int k0 = kstep * 64;
    __syncthreads();  // previous compute reads done before overwrite
    {  // X stage: fp32 nt-load -> fp16 -> swizzled ds_write_b128
      const int r = tid >> 2;
      const int cb0 = (tid & 3) * 2;
      const float* src = X + (long)(rowbase + r) * 512 + k0 + (tid & 3) * 16;
      float xv[16];
#pragma unroll
      for (int u = 0; u < 4; ++u) {
        const f32x4 v = __builtin_nontemporal_load((const f32x4*)(src + 4 * u));
        xv[4 * u + 0] = v[0]; xv[4 * u + 1] = v[1];
        xv[4 * u + 2] = v[2]; xv[4 * u + 3] = v[3];
      }
      unsigned short tmp[16] __attribute__((aligned(16)));
#pragma unroll
      for (int u = 0; u < 16; ++u) tmp[u] = f2h(xv[u]);
      *(uint4*)(sx + r * 128 + ((cb0 ^ (r & 7)) * 16)) = ((const uint4*)tmp)[0];
      *(uint4*)(sx + r * 128 + (((cb0 + 1) ^ (r & 7)) * 16)) = ((const uint4*)tmp)[1];
    }
    // W stage: global_load_lds, linear LDS dest + inverse-swizzled global source
#pragma unroll
    for (int i = 0; i < 8; ++i) {
      const int off = w * 8192 + i * 1024 + lane * 16;
      const int row = off >> 7;
      const int lcb = (lane & 7) ^ (row & 7);
      gload16(Wb + (long)row * 512 + k0 + lcb * 8, sw + w * 8192 + i * 1024);
    }
    __syncthreads();
#pragma unroll
    for (int ks = 0; ks < 2; ++ks) {
      const int rl = 16 * w + cc;
      const f16x8 af = *(const f16x8*)(sx + rl * 128 + (((h + 4 * ks) ^ (rl & 7)) * 16));
#pragma unroll
      for (int nf = 0; nf < 16; ++nf) {
        const int n = cc + 16 * nf;
        const f16x8 bf = *(const f16x8*)(sw + n * 128 + (((h + 4 * ks) ^ (n & 7)) * 16));
        acc[nf] = __builtin_amdgcn_mfma_f32_16x16x32_f16(af, bf, acc[nf], 0, 0, 0);
      }
    }
  }
#pragma unroll
  for (int nf = 0; nf < 16; ++nf) {
    const float bv = bias[cc + 16 * nf];
#pragma unroll
    for (int r = 0; r < 4; ++r) {
      const long grow = rowbase + 16 * w + 4 * h + r;
      out[grow * 256 + cc + 16 * nf] = f2h((acc[nf][r] + bv) * sc);
    }
  }
}

// ---------------- flash attention (r21 -- the validated optimum, restored) ----------------
// 256-thread block (BQ=64), KVBLK=32 dbuf, 16 q-rows/wave, 2 blocks/CU, single
// __syncthreads per iter, stage(t+1) issued at TOP of loop (r22's late-issue
// regressed -4.7 us: the early prefetch burst costs only issue slots and the
// barrier drain benefits from the longest possible in-flight window).
// log2-domain scores + native exp2; defer-max THR=12; fp16 normalized partials.
__global__ __launch_bounds__(256, 2) void attn_kernel(
    const unsigned short* __restrict__ Qb, const unsigned short* __restrict__ Kb,
    const unsigned short* __restrict__ Vt, float* __restrict__ out0,
    unsigned short* __restrict__ p16, float2* __restrict__ stats,
    int* __restrict__ cnt, int nsplit, int nchunks) {
  extern __shared__ char smem[];
  const int tid = threadIdx.x;
  const int lane = tid & 63, w = tid >> 6;
  const int h = lane >> 4, c = lane & 15;

  // ---- claim a work item from this XCD's chunk (exactly-once: tickets <32) ----
  int* s_item_p = (int*)(smem + 69632);
  if (tid == 0) {
    const unsigned x = __builtin_amdgcn_s_getreg(6164) & 7u;  // HW_REG_XCC_ID(20),off0,sz4
    const int pref = (int)x * nchunks / 8;
    int item = 0;
    for (int k = 0; k < nchunks; ++k) {
      const int ch = (pref + k) % nchunks;
      const int t = atomicAdd(cnt + ch, 1);
      if (t < 32) { item = ch * 32 + t; break; }
    }
    *s_item_p = item;
  }
  __syncthreads();
  const int nid = *s_item_p;
  const int gqt = nid & 255;      // q-tile among 256 (BQ=64)
  const int split = nid >> 8;

  const int b = gqt >> 6;
  const int qrow0 = (gqt & 63) * 64;
  const long brow = (long)b * S_LEN;

  const int kv_len = S_LEN / nsplit;
  const int kv0 = split * kv_len;
  const int nit = kv_len / 32;

  // Q fragments: 16 q-rows, 8 k-steps (scale*log2e pre-folded into Q)
  f16x8 qf[8];
  {
    const unsigned short* qbase = Qb + (brow + qrow0 + w * 16 + c) * 256 + h * 8;
#pragma unroll
    for (int kk = 0; kk < 8; ++kk)
      qf[kk] = *(const f16x8*)(qbase + kk * 32);
  }

  f32x4 O[16];
  float mrun[4], lrun[4];   // log2-domain; lrun = per-lane partial (epilogue reduce)
  const f32x4 fz = {0.f, 0.f, 0.f, 0.f};
#pragma unroll
  for (int nfd = 0; nfd < 16; ++nfd) O[nfd] = fz;
#pragma unroll
  for (int r = 0; r < 4; ++r) { mrun[r] = -1e30f; lrun[r] = 0.f; }

  const unsigned short* kbB = Kb + brow * 256;
  const unsigned short* vbB = Vt + (long)b * 256 * S_LEN;

  auto stage = [&](int buf, int it) {
    const int kvb = kv0 + it * 32;
#pragma unroll
    for (int i = 0; i < 4; ++i) {
      const int off = i * 4096 + tid * 16;
      {  // K tile [32][256] fp16, rows 512B; inverse-swizzled source
        const int row = off >> 9;
        const int lcb = ((off >> 4) & 31) ^ (row & 7);
        gload16(kbB + (long)(kvb + row) * 256 + lcb * 8, smem + buf * 16384 + off);
      }
      {  // V tile [256][32] fp16, rows 64B; inverse-swizzled source (dr>>1 swizzle)
        const int drow = off >> 6;
        const int lcb = ((off >> 4) & 3) ^ ((drow >> 1) & 3);
        gload16(vbB + (long)drow * S_LEN + kvb + lcb * 8,
                smem + 32768 + buf * 16384 + off);
      }
    }
  };

  char* const pt = smem + 65536 + w * 1024;  // per-wave P [16][32] fp16, rows 64B

  stage(0, 0);
  __syncthreads();

  for (int t = 0; t < nit; ++t) {
    const int buf = t & 1;
    if (t + 1 < nit) stage(buf ^ 1, t + 1);   // prefetch into other buffer
    const char* kt = smem + buf * 16384;
    const char* vl = smem + 32768 + buf * 16384;

    // ---- QK^T ----
    f32x4 s[2];
    s[0] = fz; s[1] = fz;
    __builtin_amdgcn_s_setprio(1);
#pragma unroll
    for (int kk = 0; kk < 8; ++kk) {
#pragma unroll
      for (int nf = 0; nf < 2; ++nf) {
        const int r = c + 16 * nf;                  // kv row 0..31
        const int cb = ((4 * kk + h) ^ (r & 7)) & 31;
        const f16x8 kf = *(const f16x8*)(kt + r * 512 + cb * 16);
        s[nf] = __builtin_amdgcn_mfma_f32_16x16x32_f16(qf[kk], kf, s[nf], 0, 0, 0);
      }
    }
    __builtin_amdgcn_s_setprio(0);

    // ---- online softmax with defer-max (THR=12, log2 domain, native exp2) ----
    {
      bool ok = true;
#pragma unroll
      for (int r = 0; r < 4; ++r)
        ok &= (fmaxf(s[0][r], s[1][r]) <= mrun[r] + 12.f);
      if (__all(ok)) {  // fast path: no shfl, no rescale
#pragma unroll
        for (int r = 0; r < 4; ++r) {
          const float p0 = ex2(s[0][r] - mrun[r]);
          const float p1 = ex2(s[1][r] - mrun[r]);
          s[0][r] = p0; s[1][r] = p1;
          lrun[r] += p0 + p1;
        }
      } else {          // slow path: full max-reduce + rescale (rare)
#pragma unroll
        for (int r = 0; r < 4; ++r) {
          float mx = fmaxf(s[0][r], s[1][r]);
          mx = fmaxf(mx, __shfl_xor(mx, 1));
          mx = fmaxf(mx, __shfl_xor(mx, 2));
          mx = fmaxf(mx, __shfl_xor(mx, 4));
          mx = fmaxf(mx, __shfl_xor(mx, 8));
          const float mnew = fmaxf(mrun[r], mx);
          const float alpha = ex2(mrun[r] - mnew);
          const float p0 = ex2(s[0][r] - mnew);
          const float p1 = ex2(s[1][r] - mnew);
          s[0][r] = p0; s[1][r] = p1;
          lrun[r] = lrun[r] * alpha + p0 + p1;
          mrun[r] = mnew;
#pragma unroll
          for (int nfd = 0; nfd < 16; ++nfd) O[nfd][r] *= alpha;
        }
      }
      // P -> LDS, rows R=4h+r (64B), col C=c+16nf; blk = (C>>3) ^ r ^ h
#pragma unroll
      for (int nf = 0; nf < 2; ++nf)
#pragma unroll
        for (int r = 0; r < 4; ++r) {
          const int C = c + 16 * nf;
          const int blk = ((C >> 3) ^ r ^ h) & 3;
          *(unsigned short*)(pt + (4 * h + r) * 64 + blk * 16 + (C & 7) * 2) =
              f2h(s[nf][r]);
        }
    }
    asm volatile("" ::: "memory");  // order P writes before P reads (type-punned LDS)

    // ---- P·V ----
    __builtin_amdgcn_s_setprio(1);
    {
      const f16x8 pa = *(const f16x8*)(pt + c * 64 + (((h ^ c ^ (c >> 2)) & 3) * 16));
#pragma unroll
      for (int nfd = 0; nfd < 16; ++nfd) {
        const int dr = c + 16 * nfd;
        const f16x8 vf = *(const f16x8*)(vl + dr * 64 + (((h ^ (dr >> 1)) & 3) * 16));
        O[nfd] = __builtin_amdgcn_mfma_f32_16x16x32_f16(pa, vf, O[nfd], 0, 0, 0);
      }
    }
    __builtin_amdgcn_s_setprio(0);
    __syncthreads();   // full drain: staged loads landed, all reads of buf done
  }

  // ---- epilogue: reduce per-lane l partials across the 16-lane row group ----
#pragma unroll
  for (int r = 0; r < 4; ++r) {
    float l = lrun[r];
    l += __shfl_xor(l, 1); l += __shfl_xor(l, 2);
    l += __shfl_xor(l, 4); l += __shfl_xor(l, 8);
    lrun[r] = l;
  }

  const long rowg0 = brow + qrow0 + w * 16 + 4 * h;
  float inv[4];
#pragma unroll
  for (int r = 0; r < 4; ++r) inv[r] = 1.f / lrun[r];

  if (nsplit == 1) {
#pragma unroll
    for (int nfd = 0; nfd < 16; ++nfd)
#pragma unroll
      for (int r = 0; r < 4; ++r)
        out0[(rowg0 + r) * 256 + c + 16 * nfd] = O[nfd][r] * inv[r];
  } else {
    // normalized fp16 partial: On = O / l  (bounded by max|v|, fp16-safe)
    unsigned short* dst = p16 + (long)split * NROWS * 256;
#pragma unroll
    for (int nfd = 0; nfd < 16; ++nfd)
#pragma unroll
      for (int r = 0; r < 4; ++r)
        dst[(rowg0 + r) * 256 + c + 16 * nfd] = f2h(O[nfd][r] * inv[r]);
    if (c == 0) {
#pragma unroll
      for (int r = 0; r < 4; ++r)
        stats[(long)split * NROWS + rowg0 + r] = make_float2(mrun[r], lrun[r]);
    }
  }
}

// ---------------- merge KV-split partials (fp16 normalized, log2-domain stats) ----------------
__global__ __launch_bounds__(256) void merge_kernel(float* __restrict__ out0,
                                                    const unsigned short* __restrict__ p16,
                                                    const float2* __restrict__ stats,
                                                    int nsplit) {
  const int i4 = blockIdx.x * 256 + threadIdx.x;  // float4 index, total 1048576
  const int row = i4 >> 6;
  float2 st[4];
#pragma unroll
  for (int s = 0; s < 4; ++s)
    st[s] = (s < nsplit) ? stats[s * NROWS + row] : make_float2(-1e30f, 0.f);
  const float m = fmaxf(fmaxf(st[0].x, st[1].x), fmaxf(st[2].x, st[3].x));
  float wgt[4], den = 0.f;
#pragma unroll
  for (int s = 0; s < 4; ++s) {
    wgt[s] = st[s].y * __builtin_amdgcn_exp2f(st[s].x - m);  // l_s * 2^(m_s - m)
    den += wgt[s];
  }
  const float invd = 1.f / den;
  float ax = 0.f, ay = 0.f, az = 0.f, aw = 0.f;
#pragma unroll
  for (int s = 0; s < 4; ++s) {
    if (s < nsplit) {
      const f16x4 v = ((const f16x4*)(p16 + (long)s * NROWS * 256))[i4];
      ax += (float)v[0] * wgt[s]; ay += (float)v[1] * wgt[s];
      az += (float)v[2] * wgt[s]; aw += (float)v[3] * wgt[s];
    }
  }
  const f32x4 res = {ax * invd, ay * invd, az * invd, aw * invd};
  ((f32x4*)out0)[i4] = res;
}

extern "C" void kernel_launch(void* const* d_in, const int* in_sizes, int n_in,
                              void* d_out, int out_size, void* d_ws, size_t ws_size,
                              hipStream_t stream) {
  const float* query = (const float*)d_in[0];
  const float* key   = (const float*)d_in[1];
  const float* value = (const float*)d_in[2];
  const float* Wq    = (const float*)d_in[3];
  const float* bq    = (const float*)d_in[4];
  const float* Wk    = (const float*)d_in[5];
  const float* bk    = (const float*)d_in[6];
  const float* scale = (const float*)d_in[7];
  float* out = (float*)d_out;

  char* ws = (char*)d_ws;
  unsigned short* Wqb = (unsigned short*)(ws);            // 256 KB
  unsigned short* Wkb = (unsigned short*)(ws + 262144);   // 256 KB
  unsigned short* Qb  = (unsigned short*)(ws + 524288);   // 8 MB
  unsigned short* Kb  = (unsigned short*)(ws + 8912896);  // 8 MB
  unsigned short* Vt  = (unsigned short*)(ws + 17301504); // 8 MB
  int* cnt            = (int*)(ws + 25690112);            // 4 KB
  float2* stats       = (float2*)(ws + 25694208);         // 512 KB
  unsigned short* p16 = (unsigned short*)(ws + 26218496); // 2 x 8 MB fp16 partials

  int nsplit = 1;
  if (ws_size >= 42995712) nsplit = 2;   // BQ=64: 512 blocks = exactly 2/CU
  const int nblk = 256 * nsplit;
  const int nchunks = nblk / 32;

  hipMemsetAsync(cnt, 0, 64, stream);
  cw_kernel<<<64, 256, 0, stream>>>(Wq, Wk, Wqb, Wkb);
  prep_kernel<<<1536, 256, 0, stream>>>(query, key, Wqb, Wkb, bq, bk, Qb, Kb,
                                        scale, value, Vt);
  hipFuncSetAttribute((const void*)attn_kernel,
                      hipFuncAttributeMaxDynamicSharedMemorySize, 69648);
  attn_kernel<<<nblk, 256, 69648, stream>>>(Qb, Kb, Vt, out, p16,
                                            stats, cnt, nsplit, nchunks);
  if (nsplit > 1)
    merge_kernel<<<4096, 256, 0, stream>>>(out, p16, stats, nsplit);
}